// Round 2
// baseline (625.883 us; speedup 1.0000x reference)
//
#include <hip/hip_runtime.h>
#include <hip/hip_fp16.h>

// Problem constants (fixed-size problem)
#define NNODES 100000
#define NEDGES 1600000
#define IN_C   128
#define HID_C  128
#define OUT_C  64

// Padded adjacency: deg ~ Poisson(16); P(deg>=64) ~ 3e-22/node. Overflow
// list keeps exactness for any input.
#define CAP     64
#define OVF_MAX 4096

// R9: two-pass binned adjacency build (replaces the 8x-scan fill_fused that
// was stuck at 1.6 TB/s / 74 us from writeback thrash + read amplification).
// Bucket = dst >> 7 (128 nodes); expected edges/bucket = Poisson(2048),
// BCAP = 3072 is a ~23-sigma guard (ovfA + fixup keep exactness regardless).
#define BUCKET_SHIFT 7
#define BUCKET_NODES 128
#define NB ((NNODES + BUCKET_NODES - 1) / BUCKET_NODES)  // 782
#define BCAP 3072

typedef __attribute__((ext_vector_type(8))) _Float16 half8;
typedef __attribute__((ext_vector_type(4))) _Float16 half4;
typedef __attribute__((ext_vector_type(4))) float floatx4;

// ---------------------------------------------------------------------------
// Index width handling (int64 per reference vs int32 from JAX default)
// ---------------------------------------------------------------------------
__device__ __forceinline__ long long load_idx(const void* p, long long i, int is64) {
  return is64 ? ((const long long*)p)[i] : (long long)((const int*)p)[i];
}

__global__ void detect_idx_kernel(const void* eidx, int* flag) {
  const unsigned* w = (const unsigned*)eidx;
  int lane = threadIdx.x & 63;
  unsigned v = w[2 * lane + 1];
  unsigned long long bad = __ballot(v != 0u);
  if (lane == 0) *flag = (bad == 0ull) ? 1 : 0;
}

// ===========================================================================
// Adjacency build: two-pass binned counting sort
// ===========================================================================

__global__ void zero_misc_kernel(int* bcnt, int* ovf_cnt, int* ovfA_cnt) {
  int i = blockIdx.x * 256 + threadIdx.x;
  if (i < NB) bcnt[i] = 0;
  if (i == 0) { *ovf_cnt = 0; *ovfA_cnt = 0; }
}

// Pass A: one thread per edge. Read int64 edge list once, append packed
// (src | dlocal<<17) to the dst-bucket. Appends hit sequential slots ->
// bucket lines fill fully before eviction (no writeback thrash).
__global__ __launch_bounds__(256) void binA_kernel(const void* __restrict__ eidx,
                                                   const int* __restrict__ flag,
                                                   int* __restrict__ bcnt,
                                                   unsigned* __restrict__ buf,
                                                   int* __restrict__ ovfA_cnt,
                                                   int2* __restrict__ ovfA) {
  int e = blockIdx.x * 256 + threadIdx.x;
  if (e >= NEDGES) return;
  int is64 = *flag;
  int s = (int)load_idx(eidx, e, is64);
  int d = (int)load_idx(eidx, (long long)NEDGES + e, is64);
  int b = d >> BUCKET_SHIFT;
  int k = atomicAdd(&bcnt[b], 1);
  if (k < BCAP) {
    buf[(size_t)b * BCAP + k] = (unsigned)s | ((unsigned)(d & (BUCKET_NODES - 1)) << 17);
  } else {
    int p = atomicAdd(ovfA_cnt, 1);
    if (p < OVF_MAX) ovfA[p] = make_int2(s, d);
  }
}

// Pass B: one block per bucket. Replay the bucket's edges through LDS
// atomics into a 128x64 LDS pad tile, then write the 32 KB tile with
// fully-coalesced int4 stores. Slots >= cnt are garbage (never read:
// gather stops at min(cnt,CAP)).
__global__ __launch_bounds__(256) void binB_kernel(const int* __restrict__ bcnt,
                                                   const unsigned* __restrict__ buf,
                                                   int* __restrict__ cnt,
                                                   int* __restrict__ pad_csr,
                                                   int* __restrict__ ovf_cnt,
                                                   int2* __restrict__ ovf) {
  __shared__ int pad[BUCKET_NODES * CAP];  // 32 KB
  __shared__ int lcnt[BUCKET_NODES];
  const int b = blockIdx.x;
  const int tid = threadIdx.x;
  const int node0 = b << BUCKET_SHIFT;

  if (tid < BUCKET_NODES) lcnt[tid] = 0;
  __syncthreads();

  const int n = min(bcnt[b], BCAP);
  for (int k = tid; k < n; k += 256) {
    unsigned u = buf[(size_t)b * BCAP + k];
    int s = (int)(u & 0x1FFFFu);
    int dl = (int)(u >> 17);
    int slot = atomicAdd(&lcnt[dl], 1);
    if (slot < CAP) {
      pad[dl * CAP + slot] = s;
    } else {
      int p = atomicAdd(ovf_cnt, 1);
      if (p < OVF_MAX) ovf[p] = make_int2(s, node0 + dl);
    }
  }
  __syncthreads();

  // write out: 128 nodes x 64 slots = 8192 ints = 2048 int4 (8 per thread)
  constexpr int I4PN = CAP / 4;  // int4 per node row (16)
  for (int q = tid; q < BUCKET_NODES * I4PN; q += 256) {
    int dl = q / I4PN;
    int gn = node0 + dl;
    if (gn < NNODES) {
      int c = (q % I4PN) * 4;
      *(int4*)&pad_csr[(size_t)gn * CAP + c] = *(const int4*)&pad[dl * CAP + c];
    }
  }
  if (tid < BUCKET_NODES && node0 + tid < NNODES) cnt[node0 + tid] = lcnt[tid];
}

// Exactness guard for pass-A bucket overflow (expected n = 0).
__global__ void fixup_kernel(const int* __restrict__ ovfA_cnt,
                             const int2* __restrict__ ovfA,
                             int* __restrict__ cnt, int* __restrict__ pad_csr,
                             int* __restrict__ ovf_cnt, int2* __restrict__ ovf) {
  int n = min(*ovfA_cnt, OVF_MAX);
  for (int t = blockIdx.x * 256 + threadIdx.x; t < n; t += gridDim.x * 256) {
    int2 p = ovfA[t];
    int k = atomicAdd(&cnt[p.y], 1);
    if (k < CAP) {
      pad_csr[(size_t)p.y * CAP + k] = p.x;
    } else {
      int q = atomicAdd(ovf_cnt, 1);
      if (q < OVF_MAX) ovf[q] = p;
    }
  }
}

__global__ void rsqrt_deg_kernel(const int* __restrict__ cnt, float* __restrict__ dinv) {
  int i = blockIdx.x * 256 + threadIdx.x;
  if (i < NNODES) dinv[i] = rsqrtf((float)(cnt[i] + 1));
}

// ---------------------------------------------------------------------------
// Gather aggregation over PRE-SCALED fp16 rows Hs[i] = h[i]*dinv[i]:
//   Out[i] = act( dinv[i] * (Hs[i] + sum_j Hs[adj(i,j)]) + bias )
// Edge lists from padded adjacency pad_csr[i*CAP .. i*CAP+min(cnt,CAP)).
// OUT16: write fp16 (hidden); else fp32 (final output).
// ---------------------------------------------------------------------------
struct F8 {
  float x0, x1, x2, x3, x4, x5, x6, x7;
};

__device__ __forceinline__ void add_h8(F8& a, const __half* p) {
  int4 r = *(const int4*)p;  // 8 halves
  const __half2* h = (const __half2*)&r;
  float2 f0 = __half22float2(h[0]);
  float2 f1 = __half22float2(h[1]);
  float2 f2 = __half22float2(h[2]);
  float2 f3 = __half22float2(h[3]);
  a.x0 += f0.x; a.x1 += f0.y; a.x2 += f1.x; a.x3 += f1.y;
  a.x4 += f2.x; a.x5 += f2.y; a.x6 += f3.x; a.x7 += f3.y;
}

template <int C, bool RELU, bool OUT16>
__global__ __launch_bounds__(256) void gather_kernel(const int* __restrict__ cnt,
                                                     const int* __restrict__ pad_csr,
                                                     const float* __restrict__ dinv,
                                                     const __half* __restrict__ Hs,
                                                     const float* __restrict__ bias,
                                                     const int* __restrict__ ovf_cnt,
                                                     const int2* __restrict__ ovf,
                                                     void* __restrict__ OutPtr) {
  constexpr int TPN = C / 8;  // threads per node (16 or 8)
  int gid = blockIdx.x * 256 + threadIdx.x;
  int i = gid / TPN;
  int c8 = (gid % TPN) * 8;
  if (i >= NNODES) return;

  const float di = dinv[i];
  const int deg = cnt[i];
  const int beg = i * CAP;
  const int end = beg + min(deg, CAP);
  const int* __restrict__ lst = pad_csr;

  F8 a0 = {}, a1 = {}, a2 = {}, a3 = {};
  add_h8(a0, &Hs[(size_t)i * C + c8]);  // self term (pre-scaled)

  int j = beg;
  for (; j + 8 <= end; j += 8) {
    int s0 = lst[j + 0], s1 = lst[j + 1], s2 = lst[j + 2], s3 = lst[j + 3];
    int s4 = lst[j + 4], s5 = lst[j + 5], s6 = lst[j + 6], s7 = lst[j + 7];
    add_h8(a0, &Hs[(size_t)s0 * C + c8]);
    add_h8(a1, &Hs[(size_t)s1 * C + c8]);
    add_h8(a2, &Hs[(size_t)s2 * C + c8]);
    add_h8(a3, &Hs[(size_t)s3 * C + c8]);
    add_h8(a0, &Hs[(size_t)s4 * C + c8]);
    add_h8(a1, &Hs[(size_t)s5 * C + c8]);
    add_h8(a2, &Hs[(size_t)s6 * C + c8]);
    add_h8(a3, &Hs[(size_t)s7 * C + c8]);
  }
  for (; j + 2 <= end; j += 2) {
    int s0 = lst[j + 0], s1 = lst[j + 1];
    add_h8(a0, &Hs[(size_t)s0 * C + c8]);
    add_h8(a1, &Hs[(size_t)s1 * C + c8]);
  }
  if (j < end) {
    add_h8(a0, &Hs[(size_t)lst[j] * C + c8]);
  }

  if (deg > CAP) {  // exactness guard; never taken for Poisson(16) degrees
    int n = min(*ovf_cnt, OVF_MAX);
    for (int t = 0; t < n; ++t) {
      int2 p = ovf[t];
      if (p.y == i) add_h8(a0, &Hs[(size_t)p.x * C + c8]);
    }
  }

  float s0 = a0.x0 + a1.x0 + a2.x0 + a3.x0;
  float s1 = a0.x1 + a1.x1 + a2.x1 + a3.x1;
  float s2 = a0.x2 + a1.x2 + a2.x2 + a3.x2;
  float s3 = a0.x3 + a1.x3 + a2.x3 + a3.x3;
  float s4 = a0.x4 + a1.x4 + a2.x4 + a3.x4;
  float s5 = a0.x5 + a1.x5 + a2.x5 + a3.x5;
  float s6 = a0.x6 + a1.x6 + a2.x6 + a3.x6;
  float s7 = a0.x7 + a1.x7 + a2.x7 + a3.x7;

  float4 b0 = *(const float4*)&bias[c8];
  float4 b1 = *(const float4*)&bias[c8 + 4];
  float o0 = fmaf(s0, di, b0.x);
  float o1 = fmaf(s1, di, b0.y);
  float o2 = fmaf(s2, di, b0.z);
  float o3 = fmaf(s3, di, b0.w);
  float o4 = fmaf(s4, di, b1.x);
  float o5 = fmaf(s5, di, b1.y);
  float o6 = fmaf(s6, di, b1.z);
  float o7 = fmaf(s7, di, b1.w);
  if (RELU) {
    o0 = o0 > 0.f ? o0 : 0.f;
    o1 = o1 > 0.f ? o1 : 0.f;
    o2 = o2 > 0.f ? o2 : 0.f;
    o3 = o3 > 0.f ? o3 : 0.f;
    o4 = o4 > 0.f ? o4 : 0.f;
    o5 = o5 > 0.f ? o5 : 0.f;
    o6 = o6 > 0.f ? o6 : 0.f;
    o7 = o7 > 0.f ? o7 : 0.f;
  }
  if (OUT16) {
    half8 hv = {(_Float16)o0, (_Float16)o1, (_Float16)o2, (_Float16)o3,
                (_Float16)o4, (_Float16)o5, (_Float16)o6, (_Float16)o7};
    *(half8*)((_Float16*)OutPtr + (size_t)i * C + c8) = hv;
  } else {
    float* Out = (float*)OutPtr;
    float4 v0 = make_float4(o0, o1, o2, o3);
    float4 v1 = make_float4(o4, o5, o6, o7);
    *(float4*)&Out[(size_t)i * C + c8] = v0;
    *(float4*)&Out[(size_t)i * C + c8 + 4] = v1;
  }
}

// ===========================================================================
// MFMA fp16 GEMM: Hout[M,N] = fp16( (X[M,K] @ W[K,N]) * scale[row] )
// 64-row M-tile per block, 4 waves x 16 rows. W in LDS transposed [n][k],
// A-tile in LDS [m][k], both fp16 with +8-half row pad.
// Fragment layouts (HW-verified m89/m91/m120):
//   A: m=lane&15, k=8*(lane>>4)+j ; B: n=lane&15, same k ;
//   D: row=4*(lane>>4)+reg, col=lane&15.
// ===========================================================================
template <int K, int N, bool A_F16>
__global__ __launch_bounds__(256) void mfma_gemm_kernel(const void* __restrict__ Xv,
                                                        const float* __restrict__ Wm,
                                                        const float* __restrict__ scale,
                                                        _Float16* __restrict__ Hout,
                                                        int M) {
  constexpr int KP = K + 8;  // padded row stride in halves (136)
  __shared__ alignas(16) _Float16 Alds[64 * KP];
  __shared__ alignas(16) _Float16 Wlds[N * KP];

  const int tid = threadIdx.x;
  const int row0 = blockIdx.x * 64;

  // ---- stage W (KxN fp32 row-major) -> Wlds[n][k] fp16, 4x4 transpose ----
  constexpr int TILES = (K / 4) * (N / 4);
  for (int tile = tid; tile < TILES; tile += 256) {
    int kt = tile / (N / 4);
    int nt = tile % (N / 4);
    const float* wp = &Wm[(4 * kt) * N + 4 * nt];
    float4 r0 = *(const float4*)(wp);
    float4 r1 = *(const float4*)(wp + N);
    float4 r2 = *(const float4*)(wp + 2 * N);
    float4 r3 = *(const float4*)(wp + 3 * N);
    half4 c0 = {(_Float16)r0.x, (_Float16)r1.x, (_Float16)r2.x, (_Float16)r3.x};
    half4 c1 = {(_Float16)r0.y, (_Float16)r1.y, (_Float16)r2.y, (_Float16)r3.y};
    half4 c2 = {(_Float16)r0.z, (_Float16)r1.z, (_Float16)r2.z, (_Float16)r3.z};
    half4 c3 = {(_Float16)r0.w, (_Float16)r1.w, (_Float16)r2.w, (_Float16)r3.w};
    *(half4*)&Wlds[(4 * nt + 0) * KP + 4 * kt] = c0;
    *(half4*)&Wlds[(4 * nt + 1) * KP + 4 * kt] = c1;
    *(half4*)&Wlds[(4 * nt + 2) * KP + 4 * kt] = c2;
    *(half4*)&Wlds[(4 * nt + 3) * KP + 4 * kt] = c3;
  }

  // ---- stage A tile (64 x K) -> Alds fp16 ----
  if (A_F16) {
    const _Float16* Xh = (const _Float16*)Xv;
    constexpr int H8PR = K / 8;  // half8 per row (16)
    constexpr int TOT = 64 * H8PR;
    for (int idx = tid; idx < TOT; idx += 256) {
      int lr = idx / H8PR;
      int c8 = (idx % H8PR) * 8;
      int gr = row0 + lr;
      if (gr > M - 1) gr = M - 1;
      int4 v = *(const int4*)&Xh[(size_t)gr * K + c8];
      *(int4*)&Alds[lr * KP + c8] = v;
    }
  } else {
    const float* Xf = (const float*)Xv;
    constexpr int F4PR = K / 4;  // float4 per row (32)
    constexpr int TOT = 64 * F4PR;
    for (int idx = tid; idx < TOT; idx += 256) {
      int lr = idx / F4PR;
      int c4 = (idx % F4PR) * 4;
      int gr = row0 + lr;
      if (gr > M - 1) gr = M - 1;
      float4 v = *(const float4*)&Xf[(size_t)gr * K + c4];
      half4 h = {(_Float16)v.x, (_Float16)v.y, (_Float16)v.z, (_Float16)v.w};
      *(half4*)&Alds[lr * KP + c4] = h;
    }
  }
  __syncthreads();

  // ---- compute ----
  const int w = tid >> 6;
  const int lane = tid & 63;
  const int g = lane >> 4;
  const int mi = lane & 15;
  constexpr int NT = N / 16;

  floatx4 acc[NT];
#pragma unroll
  for (int t = 0; t < NT; ++t) acc[t] = (floatx4){0.f, 0.f, 0.f, 0.f};

  const _Float16* arow = &Alds[(w * 16 + mi) * KP];
#pragma unroll
  for (int ks = 0; ks < K / 32; ++ks) {
    half8 a = *(const half8*)(arow + ks * 32 + g * 8);
#pragma unroll
    for (int t = 0; t < NT; ++t) {
      half8 b = *(const half8*)&Wlds[(t * 16 + mi) * KP + ks * 32 + g * 8];
      acc[t] = __builtin_amdgcn_mfma_f32_16x16x32_f16(a, b, acc[t], 0, 0, 0);
    }
  }

  // ---- epilogue: scale by dinv[row], store fp16 ----
#pragma unroll
  for (int r = 0; r < 4; ++r) {
    int grow = row0 + w * 16 + 4 * g + r;
    if (grow < M) {
      float s = scale[grow];
      _Float16* orow = Hout + (size_t)grow * N + mi;
#pragma unroll
      for (int t = 0; t < NT; ++t) orow[t * 16] = (_Float16)(acc[t][r] * s);
    }
  }
}

// ===========================================================================
// Launch
// ===========================================================================
extern "C" void kernel_launch(void* const* d_in, const int* in_sizes, int n_in,
                              void* d_out, int out_size, void* d_ws, size_t ws_size,
                              hipStream_t stream) {
  const float* x = (const float*)d_in[0];
  const void* eidx = d_in[1];
  const float* W1 = (const float*)d_in[2];
  const float* b1 = (const float*)d_in[3];
  const float* W2 = (const float*)d_in[4];
  const float* b2 = (const float*)d_in[5];
  float* out = (float*)d_out;
  char* ws = (char*)d_ws;

  // Workspace layout (512B-aligned, ~87.3 MB; harness provides >=110 MB):
  int*      flag     = (int*)(ws + 0);             //         4 B
  int*      ovf_cnt  = (int*)(ws + 512);           //         4 B
  int*      ovfA_cnt = (int*)(ws + 1024);          //         4 B
  int*      bcnt     = (int*)(ws + 1536);          //     3,128 B (NB=782)
  int*      cnt      = (int*)(ws + 8192);          //   400,000 B
  float*    dinv     = (float*)(ws + 408576);      //   400,000 B
  int2*     ovf      = (int2*)(ws + 809472);       //    32,768 B
  int2*     ovfA     = (int2*)(ws + 842752);       //    32,768 B
  unsigned* buf      = (unsigned*)(ws + 876032);   // 9,633,792 B (782*3072*4)
  int*      pad_csr  = (int*)(ws + 10510336);      // 25,600,000 B (100k x 64)
  _Float16* h1       = (_Float16*)(ws + 36110848); // 25,600,000 B (fp16 Hs)
  _Float16* hidden   = (_Float16*)(ws + 61711360); // 25,600,000 B (fp16)
  _Float16* h2 = h1;

  detect_idx_kernel<<<1, 64, 0, stream>>>(eidx, flag);
  zero_misc_kernel<<<(NB + 255) / 256, 256, 0, stream>>>(bcnt, ovf_cnt, ovfA_cnt);
  binA_kernel<<<(NEDGES + 255) / 256, 256, 0, stream>>>(eidx, flag, bcnt, buf,
                                                        ovfA_cnt, ovfA);
  binB_kernel<<<NB, 256, 0, stream>>>(bcnt, buf, cnt, pad_csr, ovf_cnt, ovf);
  fixup_kernel<<<1, 256, 0, stream>>>(ovfA_cnt, ovfA, cnt, pad_csr, ovf_cnt, ovf);
  rsqrt_deg_kernel<<<(NNODES + 255) / 256, 256, 0, stream>>>(cnt, dinv);

  const int GB = (NNODES + 63) / 64;  // 1563 M-tiles

  // Layer 1: Hs1 = fp16((x @ W1) * dinv); hidden = fp16(relu(di*(Hs1[i]+sum)+b1))
  mfma_gemm_kernel<IN_C, HID_C, false>
      <<<GB, 256, 0, stream>>>(x, W1, dinv, h1, NNODES);
  gather_kernel<HID_C, true, true>
      <<<(NNODES * (HID_C / 8) + 255) / 256, 256, 0, stream>>>(cnt, pad_csr, dinv,
                                                               (const __half*)h1, b1,
                                                               ovf_cnt, ovf, hidden);
  // Layer 2: Hs2 = fp16((hidden @ W2) * dinv); out = di*(Hs2[i]+sum)+b2 (fp32)
  mfma_gemm_kernel<HID_C, OUT_C, true>
      <<<GB, 256, 0, stream>>>(hidden, W2, dinv, h2, NNODES);
  gather_kernel<OUT_C, false, false>
      <<<(NNODES * (OUT_C / 8) + 255) / 256, 256, 0, stream>>>(cnt, pad_csr, dinv,
                                                               (const __half*)h2, b2,
                                                               ovf_cnt, ovf, out);
}

// Round 4
// 309.081 us; speedup vs baseline: 2.0250x; 2.0250x over previous
//
#include <hip/hip_runtime.h>
#include <hip/hip_fp16.h>

// Problem constants (fixed-size problem)
#define NNODES 100000
#define NEDGES 1600000
#define IN_C   128
#define HID_C  128
#define OUT_C  64

// Padded adjacency: deg ~ Poisson(16); P(deg>=64) ~ 3e-22/node. Overflow
// list keeps exactness for any input.
#define CAP     64
#define OVF_MAX 4096

// R10/R11: two-pass binned build with 16-way STRIPED bucket counters/buffers.
// R9's binA serialized (377 us, VALUBusy 0.2%): 1.6M atomics on 782 counter
// addresses (2046/address) packed 16/cacheline -> ~49 lines ping-ponging
// across all 8 XCDs. Striping by (blockIdx & 15) makes each counter line and
// each sub-list tail XCD-local (round-robin dispatch: stripe%8 = XCD), and
// cuts per-address chains to ~128 same-XCD L2 atomics.
// (R11 = R10 resubmit: container failed twice, infra flake; source audited,
// no OOB/LDS/loop hazard found.)
#define BUCKET_SHIFT 7
#define BUCKET_NODES 128
#define NB ((NNODES + BUCKET_NODES - 1) / BUCKET_NODES)  // 782
#define STRIPES 16
#define SUBCAP 256   // expected 128/sub-bucket (Poisson, ~11 sigma guard)

typedef __attribute__((ext_vector_type(8))) _Float16 half8;
typedef __attribute__((ext_vector_type(4))) _Float16 half4;
typedef __attribute__((ext_vector_type(4))) float floatx4;

// ---------------------------------------------------------------------------
// Index width handling (int64 per reference vs int32 from JAX default)
// ---------------------------------------------------------------------------
__device__ __forceinline__ long long load_idx(const void* p, long long i, int is64) {
  return is64 ? ((const long long*)p)[i] : (long long)((const int*)p)[i];
}

__global__ void detect_idx_kernel(const void* eidx, int* flag) {
  const unsigned* w = (const unsigned*)eidx;
  int lane = threadIdx.x & 63;
  unsigned v = w[2 * lane + 1];
  unsigned long long bad = __ballot(v != 0u);
  if (lane == 0) *flag = (bad == 0ull) ? 1 : 0;
}

// ===========================================================================
// Adjacency build: two-pass binned counting sort (striped)
// ===========================================================================

__global__ void zero_misc_kernel(int* bcnt, int* ovf_cnt, int* ovfA_cnt) {
  int i = blockIdx.x * 256 + threadIdx.x;
  if (i < STRIPES * NB) bcnt[i] = 0;
  if (i == 0) { *ovf_cnt = 0; *ovfA_cnt = 0; }
}

// Pass A: one thread per edge. Read int64 edge list once, append packed
// (src | dlocal<<17) to the dst-bucket's stripe-local sub-list.
__global__ __launch_bounds__(256) void binA_kernel(const void* __restrict__ eidx,
                                                   const int* __restrict__ flag,
                                                   int* __restrict__ bcnt,
                                                   unsigned* __restrict__ buf,
                                                   int* __restrict__ ovfA_cnt,
                                                   int2* __restrict__ ovfA) {
  int e = blockIdx.x * 256 + threadIdx.x;
  if (e >= NEDGES) return;
  const int st = blockIdx.x & (STRIPES - 1);
  int is64 = *flag;
  int s = (int)load_idx(eidx, e, is64);
  int d = (int)load_idx(eidx, (long long)NEDGES + e, is64);
  int b = d >> BUCKET_SHIFT;
  int k = atomicAdd(&bcnt[st * NB + b], 1);  // stripe-major: line is XCD-local
  if (k < SUBCAP) {
    buf[((size_t)b * STRIPES + st) * SUBCAP + k] =
        (unsigned)s | ((unsigned)(d & (BUCKET_NODES - 1)) << 17);
  } else {
    int p = atomicAdd(ovfA_cnt, 1);
    if (p < OVF_MAX) ovfA[p] = make_int2(s, d);
  }
}

// Pass B: one block per bucket. Replay the bucket's 16 sub-lists through LDS
// atomics into a 128x64 LDS pad tile, then write the 32 KB tile with
// fully-coalesced int4 stores. Slots >= cnt are garbage (never read:
// gather stops at min(cnt,CAP)).
__global__ __launch_bounds__(256) void binB_kernel(const int* __restrict__ bcnt,
                                                   const unsigned* __restrict__ buf,
                                                   int* __restrict__ cnt,
                                                   int* __restrict__ pad_csr,
                                                   int* __restrict__ ovf_cnt,
                                                   int2* __restrict__ ovf) {
  __shared__ int pad[BUCKET_NODES * CAP];  // 32 KB
  __shared__ int lcnt[BUCKET_NODES];
  __shared__ int scnt[STRIPES];
  const int b = blockIdx.x;
  const int tid = threadIdx.x;
  const int node0 = b << BUCKET_SHIFT;

  if (tid < BUCKET_NODES) lcnt[tid] = 0;
  if (tid < STRIPES) scnt[tid] = min(bcnt[tid * NB + b], SUBCAP);
  __syncthreads();

  // flattened over 16 sub-lists x SUBCAP slots (SUBCAP=256 -> k>>8 = stripe)
  for (int k = tid; k < STRIPES * SUBCAP; k += 256) {
    int st = k >> 8;
    int idx = k & (SUBCAP - 1);
    if (idx < scnt[st]) {
      unsigned u = buf[(size_t)b * (STRIPES * SUBCAP) + k];
      int s = (int)(u & 0x1FFFFu);
      int dl = (int)(u >> 17);
      int slot = atomicAdd(&lcnt[dl], 1);
      if (slot < CAP) {
        pad[dl * CAP + slot] = s;
      } else {
        int p = atomicAdd(ovf_cnt, 1);
        if (p < OVF_MAX) ovf[p] = make_int2(s, node0 + dl);
      }
    }
  }
  __syncthreads();

  // write out: 128 nodes x 64 slots = 8192 ints = 2048 int4 (8 per thread)
  constexpr int I4PN = CAP / 4;  // int4 per node row (16)
  for (int q = tid; q < BUCKET_NODES * I4PN; q += 256) {
    int dl = q / I4PN;
    int gn = node0 + dl;
    if (gn < NNODES) {
      int c = (q % I4PN) * 4;
      *(int4*)&pad_csr[(size_t)gn * CAP + c] = *(const int4*)&pad[dl * CAP + c];
    }
  }
  if (tid < BUCKET_NODES && node0 + tid < NNODES) cnt[node0 + tid] = lcnt[tid];
}

// Exactness guard for pass-A sub-bucket overflow (expected n = 0).
__global__ void fixup_kernel(const int* __restrict__ ovfA_cnt,
                             const int2* __restrict__ ovfA,
                             int* __restrict__ cnt, int* __restrict__ pad_csr,
                             int* __restrict__ ovf_cnt, int2* __restrict__ ovf) {
  int n = min(*ovfA_cnt, OVF_MAX);
  for (int t = blockIdx.x * 256 + threadIdx.x; t < n; t += gridDim.x * 256) {
    int2 p = ovfA[t];
    int k = atomicAdd(&cnt[p.y], 1);
    if (k < CAP) {
      pad_csr[(size_t)p.y * CAP + k] = p.x;
    } else {
      int q = atomicAdd(ovf_cnt, 1);
      if (q < OVF_MAX) ovf[q] = p;
    }
  }
}

__global__ void rsqrt_deg_kernel(const int* __restrict__ cnt, float* __restrict__ dinv) {
  int i = blockIdx.x * 256 + threadIdx.x;
  if (i < NNODES) dinv[i] = rsqrtf((float)(cnt[i] + 1));
}

// ---------------------------------------------------------------------------
// Gather aggregation over PRE-SCALED fp16 rows Hs[i] = h[i]*dinv[i]:
//   Out[i] = act( dinv[i] * (Hs[i] + sum_j Hs[adj(i,j)]) + bias )
// Edge lists from padded adjacency pad_csr[i*CAP .. i*CAP+min(cnt,CAP)).
// OUT16: write fp16 (hidden); else fp32 (final output).
// ---------------------------------------------------------------------------
struct F8 {
  float x0, x1, x2, x3, x4, x5, x6, x7;
};

__device__ __forceinline__ void add_h8(F8& a, const __half* p) {
  int4 r = *(const int4*)p;  // 8 halves
  const __half2* h = (const __half2*)&r;
  float2 f0 = __half22float2(h[0]);
  float2 f1 = __half22float2(h[1]);
  float2 f2 = __half22float2(h[2]);
  float2 f3 = __half22float2(h[3]);
  a.x0 += f0.x; a.x1 += f0.y; a.x2 += f1.x; a.x3 += f1.y;
  a.x4 += f2.x; a.x5 += f2.y; a.x6 += f3.x; a.x7 += f3.y;
}

template <int C, bool RELU, bool OUT16>
__global__ __launch_bounds__(256) void gather_kernel(const int* __restrict__ cnt,
                                                     const int* __restrict__ pad_csr,
                                                     const float* __restrict__ dinv,
                                                     const __half* __restrict__ Hs,
                                                     const float* __restrict__ bias,
                                                     const int* __restrict__ ovf_cnt,
                                                     const int2* __restrict__ ovf,
                                                     void* __restrict__ OutPtr) {
  constexpr int TPN = C / 8;  // threads per node (16 or 8)
  int gid = blockIdx.x * 256 + threadIdx.x;
  int i = gid / TPN;
  int c8 = (gid % TPN) * 8;
  if (i >= NNODES) return;

  const float di = dinv[i];
  const int deg = cnt[i];
  const int beg = i * CAP;
  const int end = beg + min(deg, CAP);
  const int* __restrict__ lst = pad_csr;

  F8 a0 = {}, a1 = {}, a2 = {}, a3 = {};
  add_h8(a0, &Hs[(size_t)i * C + c8]);  // self term (pre-scaled)

  int j = beg;
  for (; j + 8 <= end; j += 8) {
    int s0 = lst[j + 0], s1 = lst[j + 1], s2 = lst[j + 2], s3 = lst[j + 3];
    int s4 = lst[j + 4], s5 = lst[j + 5], s6 = lst[j + 6], s7 = lst[j + 7];
    add_h8(a0, &Hs[(size_t)s0 * C + c8]);
    add_h8(a1, &Hs[(size_t)s1 * C + c8]);
    add_h8(a2, &Hs[(size_t)s2 * C + c8]);
    add_h8(a3, &Hs[(size_t)s3 * C + c8]);
    add_h8(a0, &Hs[(size_t)s4 * C + c8]);
    add_h8(a1, &Hs[(size_t)s5 * C + c8]);
    add_h8(a2, &Hs[(size_t)s6 * C + c8]);
    add_h8(a3, &Hs[(size_t)s7 * C + c8]);
  }
  for (; j + 2 <= end; j += 2) {
    int s0 = lst[j + 0], s1 = lst[j + 1];
    add_h8(a0, &Hs[(size_t)s0 * C + c8]);
    add_h8(a1, &Hs[(size_t)s1 * C + c8]);
  }
  if (j < end) {
    add_h8(a0, &Hs[(size_t)lst[j] * C + c8]);
  }

  if (deg > CAP) {  // exactness guard; never taken for Poisson(16) degrees
    int n = min(*ovf_cnt, OVF_MAX);
    for (int t = 0; t < n; ++t) {
      int2 p = ovf[t];
      if (p.y == i) add_h8(a0, &Hs[(size_t)p.x * C + c8]);
    }
  }

  float s0 = a0.x0 + a1.x0 + a2.x0 + a3.x0;
  float s1 = a0.x1 + a1.x1 + a2.x1 + a3.x1;
  float s2 = a0.x2 + a1.x2 + a2.x2 + a3.x2;
  float s3 = a0.x3 + a1.x3 + a2.x3 + a3.x3;
  float s4 = a0.x4 + a1.x4 + a2.x4 + a3.x4;
  float s5 = a0.x5 + a1.x5 + a2.x5 + a3.x5;
  float s6 = a0.x6 + a1.x6 + a2.x6 + a3.x6;
  float s7 = a0.x7 + a1.x7 + a2.x7 + a3.x7;

  float4 b0 = *(const float4*)&bias[c8];
  float4 b1 = *(const float4*)&bias[c8 + 4];
  float o0 = fmaf(s0, di, b0.x);
  float o1 = fmaf(s1, di, b0.y);
  float o2 = fmaf(s2, di, b0.z);
  float o3 = fmaf(s3, di, b0.w);
  float o4 = fmaf(s4, di, b1.x);
  float o5 = fmaf(s5, di, b1.y);
  float o6 = fmaf(s6, di, b1.z);
  float o7 = fmaf(s7, di, b1.w);
  if (RELU) {
    o0 = o0 > 0.f ? o0 : 0.f;
    o1 = o1 > 0.f ? o1 : 0.f;
    o2 = o2 > 0.f ? o2 : 0.f;
    o3 = o3 > 0.f ? o3 : 0.f;
    o4 = o4 > 0.f ? o4 : 0.f;
    o5 = o5 > 0.f ? o5 : 0.f;
    o6 = o6 > 0.f ? o6 : 0.f;
    o7 = o7 > 0.f ? o7 : 0.f;
  }
  if (OUT16) {
    half8 hv = {(_Float16)o0, (_Float16)o1, (_Float16)o2, (_Float16)o3,
                (_Float16)o4, (_Float16)o5, (_Float16)o6, (_Float16)o7};
    *(half8*)((_Float16*)OutPtr + (size_t)i * C + c8) = hv;
  } else {
    float* Out = (float*)OutPtr;
    float4 v0 = make_float4(o0, o1, o2, o3);
    float4 v1 = make_float4(o4, o5, o6, o7);
    *(float4*)&Out[(size_t)i * C + c8] = v0;
    *(float4*)&Out[(size_t)i * C + c8 + 4] = v1;
  }
}

// ===========================================================================
// MFMA fp16 GEMM: Hout[M,N] = fp16( (X[M,K] @ W[K,N]) * scale[row] )
// 64-row M-tile per block, 4 waves x 16 rows. W in LDS transposed [n][k],
// A-tile in LDS [m][k], both fp16 with +8-half row pad.
// Fragment layouts (HW-verified m89/m91/m120):
//   A: m=lane&15, k=8*(lane>>4)+j ; B: n=lane&15, same k ;
//   D: row=4*(lane>>4)+reg, col=lane&15.
// ===========================================================================
template <int K, int N, bool A_F16>
__global__ __launch_bounds__(256) void mfma_gemm_kernel(const void* __restrict__ Xv,
                                                        const float* __restrict__ Wm,
                                                        const float* __restrict__ scale,
                                                        _Float16* __restrict__ Hout,
                                                        int M) {
  constexpr int KP = K + 8;  // padded row stride in halves (136)
  __shared__ alignas(16) _Float16 Alds[64 * KP];
  __shared__ alignas(16) _Float16 Wlds[N * KP];

  const int tid = threadIdx.x;
  const int row0 = blockIdx.x * 64;

  // ---- stage W (KxN fp32 row-major) -> Wlds[n][k] fp16, 4x4 transpose ----
  constexpr int TILES = (K / 4) * (N / 4);
  for (int tile = tid; tile < TILES; tile += 256) {
    int kt = tile / (N / 4);
    int nt = tile % (N / 4);
    const float* wp = &Wm[(4 * kt) * N + 4 * nt];
    float4 r0 = *(const float4*)(wp);
    float4 r1 = *(const float4*)(wp + N);
    float4 r2 = *(const float4*)(wp + 2 * N);
    float4 r3 = *(const float4*)(wp + 3 * N);
    half4 c0 = {(_Float16)r0.x, (_Float16)r1.x, (_Float16)r2.x, (_Float16)r3.x};
    half4 c1 = {(_Float16)r0.y, (_Float16)r1.y, (_Float16)r2.y, (_Float16)r3.y};
    half4 c2 = {(_Float16)r0.z, (_Float16)r1.z, (_Float16)r2.z, (_Float16)r3.z};
    half4 c3 = {(_Float16)r0.w, (_Float16)r1.w, (_Float16)r2.w, (_Float16)r3.w};
    *(half4*)&Wlds[(4 * nt + 0) * KP + 4 * kt] = c0;
    *(half4*)&Wlds[(4 * nt + 1) * KP + 4 * kt] = c1;
    *(half4*)&Wlds[(4 * nt + 2) * KP + 4 * kt] = c2;
    *(half4*)&Wlds[(4 * nt + 3) * KP + 4 * kt] = c3;
  }

  // ---- stage A tile (64 x K) -> Alds fp16 ----
  if (A_F16) {
    const _Float16* Xh = (const _Float16*)Xv;
    constexpr int H8PR = K / 8;  // half8 per row (16)
    constexpr int TOT = 64 * H8PR;
    for (int idx = tid; idx < TOT; idx += 256) {
      int lr = idx / H8PR;
      int c8 = (idx % H8PR) * 8;
      int gr = row0 + lr;
      if (gr > M - 1) gr = M - 1;
      int4 v = *(const int4*)&Xh[(size_t)gr * K + c8];
      *(int4*)&Alds[lr * KP + c8] = v;
    }
  } else {
    const float* Xf = (const float*)Xv;
    constexpr int F4PR = K / 4;  // float4 per row (32)
    constexpr int TOT = 64 * F4PR;
    for (int idx = tid; idx < TOT; idx += 256) {
      int lr = idx / F4PR;
      int c4 = (idx % F4PR) * 4;
      int gr = row0 + lr;
      if (gr > M - 1) gr = M - 1;
      float4 v = *(const float4*)&Xf[(size_t)gr * K + c4];
      half4 h = {(_Float16)v.x, (_Float16)v.y, (_Float16)v.z, (_Float16)v.w};
      *(half4*)&Alds[lr * KP + c4] = h;
    }
  }
  __syncthreads();

  // ---- compute ----
  const int w = tid >> 6;
  const int lane = tid & 63;
  const int g = lane >> 4;
  const int mi = lane & 15;
  constexpr int NT = N / 16;

  floatx4 acc[NT];
#pragma unroll
  for (int t = 0; t < NT; ++t) acc[t] = (floatx4){0.f, 0.f, 0.f, 0.f};

  const _Float16* arow = &Alds[(w * 16 + mi) * KP];
#pragma unroll
  for (int ks = 0; ks < K / 32; ++ks) {
    half8 a = *(const half8*)(arow + ks * 32 + g * 8);
#pragma unroll
    for (int t = 0; t < NT; ++t) {
      half8 b = *(const half8*)&Wlds[(t * 16 + mi) * KP + ks * 32 + g * 8];
      acc[t] = __builtin_amdgcn_mfma_f32_16x16x32_f16(a, b, acc[t], 0, 0, 0);
    }
  }

  // ---- epilogue: scale by dinv[row], store fp16 ----
#pragma unroll
  for (int r = 0; r < 4; ++r) {
    int grow = row0 + w * 16 + 4 * g + r;
    if (grow < M) {
      float s = scale[grow];
      _Float16* orow = Hout + (size_t)grow * N + mi;
#pragma unroll
      for (int t = 0; t < NT; ++t) orow[t * 16] = (_Float16)(acc[t][r] * s);
    }
  }
}

// ===========================================================================
// Launch
// ===========================================================================
extern "C" void kernel_launch(void* const* d_in, const int* in_sizes, int n_in,
                              void* d_out, int out_size, void* d_ws, size_t ws_size,
                              hipStream_t stream) {
  const float* x = (const float*)d_in[0];
  const void* eidx = d_in[1];
  const float* W1 = (const float*)d_in[2];
  const float* b1 = (const float*)d_in[3];
  const float* W2 = (const float*)d_in[4];
  const float* b2 = (const float*)d_in[5];
  float* out = (float*)d_out;
  char* ws = (char*)d_ws;

  // Workspace layout (512B-aligned, ~90.5 MB; harness provides >=110 MB):
  int*      flag     = (int*)(ws + 0);             //         4 B
  int*      ovf_cnt  = (int*)(ws + 512);           //         4 B
  int*      ovfA_cnt = (int*)(ws + 1024);          //         4 B
  int*      bcnt     = (int*)(ws + 1536);          //    50,048 B (16*782)
  int*      cnt      = (int*)(ws + 52224);         //   400,000 B
  float*    dinv     = (float*)(ws + 452608);      //   400,000 B
  int2*     ovf      = (int2*)(ws + 852992);       //    32,768 B
  int2*     ovfA     = (int2*)(ws + 885760);       //    32,768 B
  unsigned* buf      = (unsigned*)(ws + 918528);   // 12,812,288 B (782*16*256*4)
  int*      pad_csr  = (int*)(ws + 13730816);      // 25,600,000 B (100k x 64)
  _Float16* h1       = (_Float16*)(ws + 39330816); // 25,600,000 B (fp16 Hs)
  _Float16* hidden   = (_Float16*)(ws + 64930816); // 25,600,000 B (fp16)
  _Float16* h2 = h1;

  detect_idx_kernel<<<1, 64, 0, stream>>>(eidx, flag);
  zero_misc_kernel<<<(STRIPES * NB + 255) / 256, 256, 0, stream>>>(bcnt, ovf_cnt,
                                                                   ovfA_cnt);
  binA_kernel<<<(NEDGES + 255) / 256, 256, 0, stream>>>(eidx, flag, bcnt, buf,
                                                        ovfA_cnt, ovfA);
  binB_kernel<<<NB, 256, 0, stream>>>(bcnt, buf, cnt, pad_csr, ovf_cnt, ovf);
  fixup_kernel<<<1, 256, 0, stream>>>(ovfA_cnt, ovfA, cnt, pad_csr, ovf_cnt, ovf);
  rsqrt_deg_kernel<<<(NNODES + 255) / 256, 256, 0, stream>>>(cnt, dinv);

  const int GB = (NNODES + 63) / 64;  // 1563 M-tiles

  // Layer 1: Hs1 = fp16((x @ W1) * dinv); hidden = fp16(relu(di*(Hs1[i]+sum)+b1))
  mfma_gemm_kernel<IN_C, HID_C, false>
      <<<GB, 256, 0, stream>>>(x, W1, dinv, h1, NNODES);
  gather_kernel<HID_C, true, true>
      <<<(NNODES * (HID_C / 8) + 255) / 256, 256, 0, stream>>>(cnt, pad_csr, dinv,
                                                               (const __half*)h1, b1,
                                                               ovf_cnt, ovf, hidden);
  // Layer 2: Hs2 = fp16((hidden @ W2) * dinv); out = di*(Hs2[i]+sum)+b2 (fp32)
  mfma_gemm_kernel<HID_C, OUT_C, true>
      <<<GB, 256, 0, stream>>>(hidden, W2, dinv, h2, NNODES);
  gather_kernel<OUT_C, false, false>
      <<<(NNODES * (OUT_C / 8) + 255) / 256, 256, 0, stream>>>(cnt, pad_csr, dinv,
                                                               (const __half*)h2, b2,
                                                               ovf_cnt, ovf, out);
}

// Round 5
// 281.388 us; speedup vs baseline: 2.2243x; 1.0984x over previous
//
#include <hip/hip_runtime.h>
#include <hip/hip_fp16.h>

// Problem constants (fixed-size problem)
#define NNODES 100000
#define NEDGES 1600000
#define IN_C   128
#define HID_C  128
#define OUT_C  64

// Padded adjacency: deg ~ Poisson(16); P(deg>=64) ~ 3e-22/node. Overflow
// list keeps exactness for any input.
#define CAP     64
#define OVF_MAX 4096

// R12: binA v2 — block-level LDS histogram + bulk reservation.
// R10/R11's binA did 1.6M device-scope return-atomics (one per edge); striping
// fixed XCD ping-pong but not volume (build still ~77 us of the 309 total).
// Now each 4096-edge block histograms dst-buckets in LDS, reserves each
// bucket's range with ONE global atomicAdd (~300K total, 5x fewer, and the
// per-edge slot comes from an LDS counter), then places edges in ~21B
// contiguous runs. binB reads one contiguous list per bucket (coalesced) and
// computes dinv directly from lcnt (rsqrt kernel folded in).
#define BUCKET_SHIFT 7
#define BUCKET_NODES 128
#define NB ((NNODES + BUCKET_NODES - 1) / BUCKET_NODES)  // 782
#define BCAP 3072     // expected 2046/bucket (Poisson, ~23 sigma guard)
#define EB 4096       // edges per binA block
#define NBLK_A ((NEDGES + EB - 1) / EB)  // 391

typedef __attribute__((ext_vector_type(8))) _Float16 half8;
typedef __attribute__((ext_vector_type(4))) _Float16 half4;
typedef __attribute__((ext_vector_type(4))) float floatx4;

// ---------------------------------------------------------------------------
// Index width handling (int64 per reference vs int32 from JAX default)
// ---------------------------------------------------------------------------
__device__ __forceinline__ long long load_idx(const void* p, long long i, int is64) {
  return is64 ? ((const long long*)p)[i] : (long long)((const int*)p)[i];
}

__global__ void detect_idx_kernel(const void* eidx, int* flag) {
  const unsigned* w = (const unsigned*)eidx;
  int lane = threadIdx.x & 63;
  unsigned v = w[2 * lane + 1];
  unsigned long long bad = __ballot(v != 0u);
  if (lane == 0) *flag = (bad == 0ull) ? 1 : 0;
}

// ===========================================================================
// Adjacency build: two-pass binned counting sort (block-histogram reservation)
// ===========================================================================

__global__ void zero_misc_kernel(int* bcnt, int* ovf_cnt, int* ovfA_cnt) {
  int i = blockIdx.x * 256 + threadIdx.x;
  if (i < NB) bcnt[i] = 0;
  if (i == 0) { *ovf_cnt = 0; *ovfA_cnt = 0; }
}

// Pass A: per block of EB edges: LDS histogram -> one global reservation per
// non-empty bucket -> placement at base[b] + LDS-offset. Slots land in
// contiguous per-(block,bucket) runs; every slot < BCAP is written exactly
// once (ranges partition [0, bcnt[b])).
__global__ __launch_bounds__(256) void binA_kernel(const void* __restrict__ eidx,
                                                   const int* __restrict__ flag,
                                                   int* __restrict__ bcnt,
                                                   unsigned* __restrict__ buf,
                                                   int* __restrict__ ovfA_cnt,
                                                   int2* __restrict__ ovfA) {
  __shared__ int hist[NB];
  __shared__ int base[NB];
  __shared__ int ofs[NB];
  const int tid = threadIdx.x;
  const int e0 = blockIdx.x * EB;
  const int e1 = min(e0 + EB, NEDGES);
  const int is64 = *flag;

  for (int b = tid; b < NB; b += 256) { hist[b] = 0; ofs[b] = 0; }
  __syncthreads();

  // phase 1: histogram dst (dst stream will be re-read in phase 3 -> cached)
  for (int e = e0 + tid; e < e1; e += 256) {
    int d = (int)load_idx(eidx, (long long)NEDGES + e, is64);
    atomicAdd(&hist[d >> BUCKET_SHIFT], 1);
  }
  __syncthreads();

  // phase 2: bulk-reserve each bucket's range (one global atomic per bucket)
  for (int b = tid; b < NB; b += 256) {
    int h = hist[b];
    if (h > 0) base[b] = atomicAdd(&bcnt[b], h);
  }
  __syncthreads();

  // phase 3: place edges (packed src | dlocal<<17); NNODES < 2^17
  for (int e = e0 + tid; e < e1; e += 256) {
    int s = (int)load_idx(eidx, e, is64);
    int d = (int)load_idx(eidx, (long long)NEDGES + e, is64);
    int b = d >> BUCKET_SHIFT;
    int ko = atomicAdd(&ofs[b], 1);
    int slot = base[b] + ko;
    if (slot < BCAP) {
      buf[(size_t)b * BCAP + slot] =
          (unsigned)s | ((unsigned)(d & (BUCKET_NODES - 1)) << 17);
    } else {
      int p = atomicAdd(ovfA_cnt, 1);
      if (p < OVF_MAX) ovfA[p] = make_int2(s, d);
    }
  }
}

// Pass B: one block per bucket. Replay the bucket's contiguous list through
// LDS atomics into a 128x64 LDS pad tile, write the 32 KB tile with coalesced
// int4 stores, and emit cnt + dinv (rsqrt kernel folded in). Slots >= cnt are
// garbage (never read: gather stops at min(cnt,CAP)).
__global__ __launch_bounds__(256) void binB_kernel(const int* __restrict__ bcnt,
                                                   const unsigned* __restrict__ buf,
                                                   int* __restrict__ cnt,
                                                   float* __restrict__ dinv,
                                                   int* __restrict__ pad_csr,
                                                   int* __restrict__ ovf_cnt,
                                                   int2* __restrict__ ovf) {
  __shared__ int pad[BUCKET_NODES * CAP];  // 32 KB
  __shared__ int lcnt[BUCKET_NODES];
  const int b = blockIdx.x;
  const int tid = threadIdx.x;
  const int node0 = b << BUCKET_SHIFT;

  if (tid < BUCKET_NODES) lcnt[tid] = 0;
  __syncthreads();

  const int n = min(bcnt[b], BCAP);
  for (int k = tid; k < n; k += 256) {
    unsigned u = buf[(size_t)b * BCAP + k];
    int s = (int)(u & 0x1FFFFu);
    int dl = (int)(u >> 17);
    int slot = atomicAdd(&lcnt[dl], 1);
    if (slot < CAP) {
      pad[dl * CAP + slot] = s;
    } else {
      int p = atomicAdd(ovf_cnt, 1);
      if (p < OVF_MAX) ovf[p] = make_int2(s, node0 + dl);
    }
  }
  __syncthreads();

  // write out: 128 nodes x 64 slots = 8192 ints = 2048 int4 (8 per thread)
  constexpr int I4PN = CAP / 4;  // int4 per node row (16)
  for (int q = tid; q < BUCKET_NODES * I4PN; q += 256) {
    int dl = q / I4PN;
    int gn = node0 + dl;
    if (gn < NNODES) {
      int c = (q % I4PN) * 4;
      *(int4*)&pad_csr[(size_t)gn * CAP + c] = *(const int4*)&pad[dl * CAP + c];
    }
  }
  if (tid < BUCKET_NODES && node0 + tid < NNODES) {
    int c = lcnt[tid];
    cnt[node0 + tid] = c;
    dinv[node0 + tid] = rsqrtf((float)(c + 1));
  }
}

// Exactness guard for pass-A bucket overflow (expected n = 0). Single block;
// patches cnt, pad_csr AND dinv for affected nodes.
__global__ void fixup_kernel(const int* __restrict__ ovfA_cnt,
                             const int2* __restrict__ ovfA,
                             int* __restrict__ cnt, float* __restrict__ dinv,
                             int* __restrict__ pad_csr,
                             int* __restrict__ ovf_cnt, int2* __restrict__ ovf) {
  int n = min(*ovfA_cnt, OVF_MAX);
  for (int t = threadIdx.x; t < n; t += 256) {
    int2 p = ovfA[t];
    int k = atomicAdd(&cnt[p.y], 1);
    if (k < CAP) {
      pad_csr[(size_t)p.y * CAP + k] = p.x;
    } else {
      int q = atomicAdd(ovf_cnt, 1);
      if (q < OVF_MAX) ovf[q] = p;
    }
  }
  __syncthreads();
  for (int t = threadIdx.x; t < n; t += 256) {
    int node = ovfA[t].y;
    dinv[node] = rsqrtf((float)(cnt[node] + 1));
  }
}

// ---------------------------------------------------------------------------
// Gather aggregation over PRE-SCALED fp16 rows Hs[i] = h[i]*dinv[i]:
//   Out[i] = act( dinv[i] * (Hs[i] + sum_j Hs[adj(i,j)]) + bias )
// Edge lists from padded adjacency pad_csr[i*CAP .. i*CAP+min(cnt,CAP)).
// OUT16: write fp16 (hidden); else fp32 (final output).
// ---------------------------------------------------------------------------
struct F8 {
  float x0, x1, x2, x3, x4, x5, x6, x7;
};

__device__ __forceinline__ void add_h8(F8& a, const __half* p) {
  int4 r = *(const int4*)p;  // 8 halves
  const __half2* h = (const __half2*)&r;
  float2 f0 = __half22float2(h[0]);
  float2 f1 = __half22float2(h[1]);
  float2 f2 = __half22float2(h[2]);
  float2 f3 = __half22float2(h[3]);
  a.x0 += f0.x; a.x1 += f0.y; a.x2 += f1.x; a.x3 += f1.y;
  a.x4 += f2.x; a.x5 += f2.y; a.x6 += f3.x; a.x7 += f3.y;
}

template <int C, bool RELU, bool OUT16>
__global__ __launch_bounds__(256) void gather_kernel(const int* __restrict__ cnt,
                                                     const int* __restrict__ pad_csr,
                                                     const float* __restrict__ dinv,
                                                     const __half* __restrict__ Hs,
                                                     const float* __restrict__ bias,
                                                     const int* __restrict__ ovf_cnt,
                                                     const int2* __restrict__ ovf,
                                                     void* __restrict__ OutPtr) {
  constexpr int TPN = C / 8;  // threads per node (16 or 8)
  int gid = blockIdx.x * 256 + threadIdx.x;
  int i = gid / TPN;
  int c8 = (gid % TPN) * 8;
  if (i >= NNODES) return;

  const float di = dinv[i];
  const int deg = cnt[i];
  const int beg = i * CAP;
  const int end = beg + min(deg, CAP);
  const int* __restrict__ lst = pad_csr;

  F8 a0 = {}, a1 = {}, a2 = {}, a3 = {};
  add_h8(a0, &Hs[(size_t)i * C + c8]);  // self term (pre-scaled)

  int j = beg;
  for (; j + 8 <= end; j += 8) {
    // lists are 256B-aligned and j-beg is a multiple of 8 -> int4-aligned
    int4 sa = *(const int4*)&lst[j];
    int4 sb = *(const int4*)&lst[j + 4];
    add_h8(a0, &Hs[(size_t)sa.x * C + c8]);
    add_h8(a1, &Hs[(size_t)sa.y * C + c8]);
    add_h8(a2, &Hs[(size_t)sa.z * C + c8]);
    add_h8(a3, &Hs[(size_t)sa.w * C + c8]);
    add_h8(a0, &Hs[(size_t)sb.x * C + c8]);
    add_h8(a1, &Hs[(size_t)sb.y * C + c8]);
    add_h8(a2, &Hs[(size_t)sb.z * C + c8]);
    add_h8(a3, &Hs[(size_t)sb.w * C + c8]);
  }
  for (; j + 2 <= end; j += 2) {
    int s0 = lst[j + 0], s1 = lst[j + 1];
    add_h8(a0, &Hs[(size_t)s0 * C + c8]);
    add_h8(a1, &Hs[(size_t)s1 * C + c8]);
  }
  if (j < end) {
    add_h8(a0, &Hs[(size_t)lst[j] * C + c8]);
  }

  if (deg > CAP) {  // exactness guard; never taken for Poisson(16) degrees
    int n = min(*ovf_cnt, OVF_MAX);
    for (int t = 0; t < n; ++t) {
      int2 p = ovf[t];
      if (p.y == i) add_h8(a0, &Hs[(size_t)p.x * C + c8]);
    }
  }

  float s0 = a0.x0 + a1.x0 + a2.x0 + a3.x0;
  float s1 = a0.x1 + a1.x1 + a2.x1 + a3.x1;
  float s2 = a0.x2 + a1.x2 + a2.x2 + a3.x2;
  float s3 = a0.x3 + a1.x3 + a2.x3 + a3.x3;
  float s4 = a0.x4 + a1.x4 + a2.x4 + a3.x4;
  float s5 = a0.x5 + a1.x5 + a2.x5 + a3.x5;
  float s6 = a0.x6 + a1.x6 + a2.x6 + a3.x6;
  float s7 = a0.x7 + a1.x7 + a2.x7 + a3.x7;

  float4 b0 = *(const float4*)&bias[c8];
  float4 b1 = *(const float4*)&bias[c8 + 4];
  float o0 = fmaf(s0, di, b0.x);
  float o1 = fmaf(s1, di, b0.y);
  float o2 = fmaf(s2, di, b0.z);
  float o3 = fmaf(s3, di, b0.w);
  float o4 = fmaf(s4, di, b1.x);
  float o5 = fmaf(s5, di, b1.y);
  float o6 = fmaf(s6, di, b1.z);
  float o7 = fmaf(s7, di, b1.w);
  if (RELU) {
    o0 = o0 > 0.f ? o0 : 0.f;
    o1 = o1 > 0.f ? o1 : 0.f;
    o2 = o2 > 0.f ? o2 : 0.f;
    o3 = o3 > 0.f ? o3 : 0.f;
    o4 = o4 > 0.f ? o4 : 0.f;
    o5 = o5 > 0.f ? o5 : 0.f;
    o6 = o6 > 0.f ? o6 : 0.f;
    o7 = o7 > 0.f ? o7 : 0.f;
  }
  if (OUT16) {
    half8 hv = {(_Float16)o0, (_Float16)o1, (_Float16)o2, (_Float16)o3,
                (_Float16)o4, (_Float16)o5, (_Float16)o6, (_Float16)o7};
    *(half8*)((_Float16*)OutPtr + (size_t)i * C + c8) = hv;
  } else {
    float* Out = (float*)OutPtr;
    float4 v0 = make_float4(o0, o1, o2, o3);
    float4 v1 = make_float4(o4, o5, o6, o7);
    *(float4*)&Out[(size_t)i * C + c8] = v0;
    *(float4*)&Out[(size_t)i * C + c8 + 4] = v1;
  }
}

// ===========================================================================
// MFMA fp16 GEMM: Hout[M,N] = fp16( (X[M,K] @ W[K,N]) * scale[row] )
// 64-row M-tile per block, 4 waves x 16 rows. W in LDS transposed [n][k],
// A-tile in LDS [m][k], both fp16 with +8-half row pad.
// Fragment layouts (HW-verified m89/m91/m120):
//   A: m=lane&15, k=8*(lane>>4)+j ; B: n=lane&15, same k ;
//   D: row=4*(lane>>4)+reg, col=lane&15.
// ===========================================================================
template <int K, int N, bool A_F16>
__global__ __launch_bounds__(256) void mfma_gemm_kernel(const void* __restrict__ Xv,
                                                        const float* __restrict__ Wm,
                                                        const float* __restrict__ scale,
                                                        _Float16* __restrict__ Hout,
                                                        int M) {
  constexpr int KP = K + 8;  // padded row stride in halves (136)
  __shared__ alignas(16) _Float16 Alds[64 * KP];
  __shared__ alignas(16) _Float16 Wlds[N * KP];

  const int tid = threadIdx.x;
  const int row0 = blockIdx.x * 64;

  // ---- stage W (KxN fp32 row-major) -> Wlds[n][k] fp16, 4x4 transpose ----
  constexpr int TILES = (K / 4) * (N / 4);
  for (int tile = tid; tile < TILES; tile += 256) {
    int kt = tile / (N / 4);
    int nt = tile % (N / 4);
    const float* wp = &Wm[(4 * kt) * N + 4 * nt];
    float4 r0 = *(const float4*)(wp);
    float4 r1 = *(const float4*)(wp + N);
    float4 r2 = *(const float4*)(wp + 2 * N);
    float4 r3 = *(const float4*)(wp + 3 * N);
    half4 c0 = {(_Float16)r0.x, (_Float16)r1.x, (_Float16)r2.x, (_Float16)r3.x};
    half4 c1 = {(_Float16)r0.y, (_Float16)r1.y, (_Float16)r2.y, (_Float16)r3.y};
    half4 c2 = {(_Float16)r0.z, (_Float16)r1.z, (_Float16)r2.z, (_Float16)r3.z};
    half4 c3 = {(_Float16)r0.w, (_Float16)r1.w, (_Float16)r2.w, (_Float16)r3.w};
    *(half4*)&Wlds[(4 * nt + 0) * KP + 4 * kt] = c0;
    *(half4*)&Wlds[(4 * nt + 1) * KP + 4 * kt] = c1;
    *(half4*)&Wlds[(4 * nt + 2) * KP + 4 * kt] = c2;
    *(half4*)&Wlds[(4 * nt + 3) * KP + 4 * kt] = c3;
  }

  // ---- stage A tile (64 x K) -> Alds fp16 ----
  if (A_F16) {
    const _Float16* Xh = (const _Float16*)Xv;
    constexpr int H8PR = K / 8;  // half8 per row (16)
    constexpr int TOT = 64 * H8PR;
    for (int idx = tid; idx < TOT; idx += 256) {
      int lr = idx / H8PR;
      int c8 = (idx % H8PR) * 8;
      int gr = row0 + lr;
      if (gr > M - 1) gr = M - 1;
      int4 v = *(const int4*)&Xh[(size_t)gr * K + c8];
      *(int4*)&Alds[lr * KP + c8] = v;
    }
  } else {
    const float* Xf = (const float*)Xv;
    constexpr int F4PR = K / 4;  // float4 per row (32)
    constexpr int TOT = 64 * F4PR;
    for (int idx = tid; idx < TOT; idx += 256) {
      int lr = idx / F4PR;
      int c4 = (idx % F4PR) * 4;
      int gr = row0 + lr;
      if (gr > M - 1) gr = M - 1;
      float4 v = *(const float4*)&Xf[(size_t)gr * K + c4];
      half4 h = {(_Float16)v.x, (_Float16)v.y, (_Float16)v.z, (_Float16)v.w};
      *(half4*)&Alds[lr * KP + c4] = h;
    }
  }
  __syncthreads();

  // ---- compute ----
  const int w = tid >> 6;
  const int lane = tid & 63;
  const int g = lane >> 4;
  const int mi = lane & 15;
  constexpr int NT = N / 16;

  floatx4 acc[NT];
#pragma unroll
  for (int t = 0; t < NT; ++t) acc[t] = (floatx4){0.f, 0.f, 0.f, 0.f};

  const _Float16* arow = &Alds[(w * 16 + mi) * KP];
#pragma unroll
  for (int ks = 0; ks < K / 32; ++ks) {
    half8 a = *(const half8*)(arow + ks * 32 + g * 8);
#pragma unroll
    for (int t = 0; t < NT; ++t) {
      half8 b = *(const half8*)&Wlds[(t * 16 + mi) * KP + ks * 32 + g * 8];
      acc[t] = __builtin_amdgcn_mfma_f32_16x16x32_f16(a, b, acc[t], 0, 0, 0);
    }
  }

  // ---- epilogue: scale by dinv[row], store fp16 ----
#pragma unroll
  for (int r = 0; r < 4; ++r) {
    int grow = row0 + w * 16 + 4 * g + r;
    if (grow < M) {
      float s = scale[grow];
      _Float16* orow = Hout + (size_t)grow * N + mi;
#pragma unroll
      for (int t = 0; t < NT; ++t) orow[t * 16] = (_Float16)(acc[t][r] * s);
    }
  }
}

// ===========================================================================
// Launch
// ===========================================================================
extern "C" void kernel_launch(void* const* d_in, const int* in_sizes, int n_in,
                              void* d_out, int out_size, void* d_ws, size_t ws_size,
                              hipStream_t stream) {
  const float* x = (const float*)d_in[0];
  const void* eidx = d_in[1];
  const float* W1 = (const float*)d_in[2];
  const float* b1 = (const float*)d_in[3];
  const float* W2 = (const float*)d_in[4];
  const float* b2 = (const float*)d_in[5];
  float* out = (float*)d_out;
  char* ws = (char*)d_ws;

  // Workspace layout (512B-aligned, ~87.3 MB; harness provides >=110 MB):
  int*      flag     = (int*)(ws + 0);             //         4 B
  int*      ovf_cnt  = (int*)(ws + 512);           //         4 B
  int*      ovfA_cnt = (int*)(ws + 1024);          //         4 B
  int*      bcnt     = (int*)(ws + 1536);          //     3,128 B (NB=782)
  int*      cnt      = (int*)(ws + 8192);          //   400,000 B
  float*    dinv     = (float*)(ws + 408576);      //   400,000 B
  int2*     ovf      = (int2*)(ws + 809472);       //    32,768 B
  int2*     ovfA     = (int2*)(ws + 842752);       //    32,768 B
  unsigned* buf      = (unsigned*)(ws + 876032);   // 9,609,216 B (782*3072*4)
  int*      pad_csr  = (int*)(ws + 10486272);      // 25,600,000 B (100k x 64)
  _Float16* h1       = (_Float16*)(ws + 36086784); // 25,600,000 B (fp16 Hs)
  _Float16* hidden   = (_Float16*)(ws + 61687296); // 25,600,000 B (fp16)
  _Float16* h2 = h1;

  detect_idx_kernel<<<1, 64, 0, stream>>>(eidx, flag);
  zero_misc_kernel<<<(NB + 255) / 256, 256, 0, stream>>>(bcnt, ovf_cnt, ovfA_cnt);
  binA_kernel<<<NBLK_A, 256, 0, stream>>>(eidx, flag, bcnt, buf, ovfA_cnt, ovfA);
  binB_kernel<<<NB, 256, 0, stream>>>(bcnt, buf, cnt, dinv, pad_csr, ovf_cnt, ovf);
  fixup_kernel<<<1, 256, 0, stream>>>(ovfA_cnt, ovfA, cnt, dinv, pad_csr,
                                      ovf_cnt, ovf);

  const int GB = (NNODES + 63) / 64;  // 1563 M-tiles

  // Layer 1: Hs1 = fp16((x @ W1) * dinv); hidden = fp16(relu(di*(Hs1[i]+sum)+b1))
  mfma_gemm_kernel<IN_C, HID_C, false>
      <<<GB, 256, 0, stream>>>(x, W1, dinv, h1, NNODES);
  gather_kernel<HID_C, true, true>
      <<<(NNODES * (HID_C / 8) + 255) / 256, 256, 0, stream>>>(cnt, pad_csr, dinv,
                                                               (const __half*)h1, b1,
                                                               ovf_cnt, ovf, hidden);
  // Layer 2: Hs2 = fp16((hidden @ W2) * dinv); out = di*(Hs2[i]+sum)+b2 (fp32)
  mfma_gemm_kernel<HID_C, OUT_C, true>
      <<<GB, 256, 0, stream>>>(hidden, W2, dinv, h2, NNODES);
  gather_kernel<OUT_C, false, false>
      <<<(NNODES * (OUT_C / 8) + 255) / 256, 256, 0, stream>>>(cnt, pad_csr, dinv,
                                                               (const __half*)h2, b2,
                                                               ovf_cnt, ovf, out);
}

// Round 6
// 276.966 us; speedup vs baseline: 2.2598x; 1.0160x over previous
//
#include <hip/hip_runtime.h>
#include <hip/hip_fp16.h>

// Problem constants (fixed-size problem)
#define NNODES 100000
#define NEDGES 1600000
#define IN_C   128
#define HID_C  128
#define OUT_C  64

// Padded adjacency: deg ~ Poisson(16); P(deg>=64) ~ 3e-22/node. Overflow
// list keeps exactness for any input.
#define CAP     64
#define OVF_MAX 4096

// R13:
//  - binA v3: decoded edges stashed in LDS during the histogram pass (eidx
//    read ONCE, was twice); bcnt padded to 1 counter / 64B line (kills the
//    16-counters-per-line cross-XCD bounce on reservation atomics);
//    reservation order rotated per block (no phase-aligned hotspot).
//  - gather v2: 16 channels/lane (TPN halves). Two independent 16B row loads
//    per edge -> 16 outstanding gathers per 8-edge batch. gather1 was 64 us
//    at 3.45 TB/s L2-fill with VALUBusy 30% / Occ 35% = latency-bound, not
//    BW-bound (table is 25.6 MB, L3-resident).
#define BUCKET_SHIFT 7
#define BUCKET_NODES 128
#define NB ((NNODES + BUCKET_NODES - 1) / BUCKET_NODES)  // 782
#define BCAP 3072     // expected 2046/bucket (Poisson, ~23 sigma guard)
#define BCNT_STRIDE 16  // one counter per 64B line
#define EB 4096       // edges per binA block
#define NBLK_A ((NEDGES + EB - 1) / EB)  // 391

typedef __attribute__((ext_vector_type(8))) _Float16 half8;
typedef __attribute__((ext_vector_type(4))) _Float16 half4;
typedef __attribute__((ext_vector_type(4))) float floatx4;

// ---------------------------------------------------------------------------
// Index width handling (int64 per reference vs int32 from JAX default)
// ---------------------------------------------------------------------------
__device__ __forceinline__ long long load_idx(const void* p, long long i, int is64) {
  return is64 ? ((const long long*)p)[i] : (long long)((const int*)p)[i];
}

__global__ void detect_idx_kernel(const void* eidx, int* flag) {
  const unsigned* w = (const unsigned*)eidx;
  int lane = threadIdx.x & 63;
  unsigned v = w[2 * lane + 1];
  unsigned long long bad = __ballot(v != 0u);
  if (lane == 0) *flag = (bad == 0ull) ? 1 : 0;
}

// ===========================================================================
// Adjacency build: two-pass binned counting sort (block-histogram reservation)
// ===========================================================================

__global__ void zero_misc_kernel(int* bcnt, int* ovf_cnt, int* ovfA_cnt) {
  int i = blockIdx.x * 256 + threadIdx.x;
  if (i < NB * BCNT_STRIDE) bcnt[i] = 0;
  if (i == 0) { *ovf_cnt = 0; *ovfA_cnt = 0; }
}

// Pass A: per block of EB edges:
//   phase 1: decode eidx once -> stash (src|dlocal, bucket) in LDS + LDS hist
//   phase 2: bulk-reserve each nonempty bucket (ONE padded global atomic),
//            iteration order rotated per block
//   phase 3: place from LDS stash at base[b] + LDS-offset
// Slots land in contiguous per-(block,bucket) runs; every slot < BCAP is
// written exactly once (ranges partition [0, bcnt[b])).
__global__ __launch_bounds__(256) void binA_kernel(const void* __restrict__ eidx,
                                                   const int* __restrict__ flag,
                                                   int* __restrict__ bcnt,
                                                   unsigned* __restrict__ buf,
                                                   int* __restrict__ ovfA_cnt,
                                                   int2* __restrict__ ovfA) {
  __shared__ unsigned se[EB];        // 16 KB: src | dlocal<<17
  __shared__ unsigned short be[EB];  //  8 KB: bucket id
  __shared__ int hist[NB];
  __shared__ int base[NB];
  __shared__ int ofs[NB];
  const int tid = threadIdx.x;
  const int e0 = blockIdx.x * EB;
  const int e1 = min(e0 + EB, NEDGES);
  const int m = e1 - e0;
  const int is64 = *flag;

  for (int b = tid; b < NB; b += 256) { hist[b] = 0; ofs[b] = 0; }
  __syncthreads();

  // phase 1: single decode pass + stash + histogram
  for (int k = tid; k < m; k += 256) {
    int e = e0 + k;
    int s = (int)load_idx(eidx, e, is64);
    int d = (int)load_idx(eidx, (long long)NEDGES + e, is64);
    int b = d >> BUCKET_SHIFT;
    se[k] = (unsigned)s | ((unsigned)(d & (BUCKET_NODES - 1)) << 17);
    be[k] = (unsigned short)b;
    atomicAdd(&hist[b], 1);
  }
  __syncthreads();

  // phase 2: reserve (rotated start -> blocks don't hit same lines in phase)
  int rot = (blockIdx.x * 131) % NB;
  for (int idx = tid; idx < NB; idx += 256) {
    int b = idx + rot;
    if (b >= NB) b -= NB;
    int h = hist[b];
    if (h > 0) base[b] = atomicAdd(&bcnt[b * BCNT_STRIDE], h);
  }
  __syncthreads();

  // phase 3: place from LDS
  for (int k = tid; k < m; k += 256) {
    unsigned u = se[k];
    int b = be[k];
    int ko = atomicAdd(&ofs[b], 1);
    int slot = base[b] + ko;
    if (slot < BCAP) {
      buf[(size_t)b * BCAP + slot] = u;
    } else {
      int p = atomicAdd(ovfA_cnt, 1);
      if (p < OVF_MAX)
        ovfA[p] = make_int2((int)(u & 0x1FFFFu),
                            (b << BUCKET_SHIFT) | (int)(u >> 17));
    }
  }
}

// Pass B: one block per bucket. Replay the bucket's contiguous list through
// LDS atomics into a 128x64 LDS pad tile, write the 32 KB tile with coalesced
// int4 stores, and emit cnt + dinv (rsqrt folded in). Slots >= cnt are
// garbage (never read: gather stops at min(cnt,CAP)).
__global__ __launch_bounds__(256) void binB_kernel(const int* __restrict__ bcnt,
                                                   const unsigned* __restrict__ buf,
                                                   int* __restrict__ cnt,
                                                   float* __restrict__ dinv,
                                                   int* __restrict__ pad_csr,
                                                   int* __restrict__ ovf_cnt,
                                                   int2* __restrict__ ovf) {
  __shared__ int pad[BUCKET_NODES * CAP];  // 32 KB
  __shared__ int lcnt[BUCKET_NODES];
  const int b = blockIdx.x;
  const int tid = threadIdx.x;
  const int node0 = b << BUCKET_SHIFT;

  if (tid < BUCKET_NODES) lcnt[tid] = 0;
  __syncthreads();

  const int n = min(bcnt[b * BCNT_STRIDE], BCAP);
  for (int k = tid; k < n; k += 256) {
    unsigned u = buf[(size_t)b * BCAP + k];
    int s = (int)(u & 0x1FFFFu);
    int dl = (int)(u >> 17);
    int slot = atomicAdd(&lcnt[dl], 1);
    if (slot < CAP) {
      pad[dl * CAP + slot] = s;
    } else {
      int p = atomicAdd(ovf_cnt, 1);
      if (p < OVF_MAX) ovf[p] = make_int2(s, node0 + dl);
    }
  }
  __syncthreads();

  // write out: 128 nodes x 64 slots = 8192 ints = 2048 int4 (8 per thread)
  constexpr int I4PN = CAP / 4;  // int4 per node row (16)
  for (int q = tid; q < BUCKET_NODES * I4PN; q += 256) {
    int dl = q / I4PN;
    int gn = node0 + dl;
    if (gn < NNODES) {
      int c = (q % I4PN) * 4;
      *(int4*)&pad_csr[(size_t)gn * CAP + c] = *(const int4*)&pad[dl * CAP + c];
    }
  }
  if (tid < BUCKET_NODES && node0 + tid < NNODES) {
    int c = lcnt[tid];
    cnt[node0 + tid] = c;
    dinv[node0 + tid] = rsqrtf((float)(c + 1));
  }
}

// Exactness guard for pass-A bucket overflow (expected n = 0). Single block;
// patches cnt, pad_csr AND dinv for affected nodes.
__global__ void fixup_kernel(const int* __restrict__ ovfA_cnt,
                             const int2* __restrict__ ovfA,
                             int* __restrict__ cnt, float* __restrict__ dinv,
                             int* __restrict__ pad_csr,
                             int* __restrict__ ovf_cnt, int2* __restrict__ ovf) {
  int n = min(*ovfA_cnt, OVF_MAX);
  for (int t = threadIdx.x; t < n; t += 256) {
    int2 p = ovfA[t];
    int k = atomicAdd(&cnt[p.y], 1);
    if (k < CAP) {
      pad_csr[(size_t)p.y * CAP + k] = p.x;
    } else {
      int q = atomicAdd(ovf_cnt, 1);
      if (q < OVF_MAX) ovf[q] = p;
    }
  }
  __syncthreads();
  for (int t = threadIdx.x; t < n; t += 256) {
    int node = ovfA[t].y;
    dinv[node] = rsqrtf((float)(cnt[node] + 1));
  }
}

// ---------------------------------------------------------------------------
// Gather aggregation over PRE-SCALED fp16 rows Hs[i] = h[i]*dinv[i]:
//   Out[i] = act( dinv[i] * (Hs[i] + sum_j Hs[adj(i,j)]) + bias )
// 16 channels per lane (TPN = C/16): two independent 16B loads per edge ->
// 2x the outstanding VMEM of the old 8-ch/lane version (latency-bound fix).
// OUT16: write fp16 (hidden); else fp32 (final output).
// ---------------------------------------------------------------------------
struct F8 {
  float x0, x1, x2, x3, x4, x5, x6, x7;
};

__device__ __forceinline__ void add_h8(F8& a, const __half* p) {
  int4 r = *(const int4*)p;  // 8 halves
  const __half2* h = (const __half2*)&r;
  float2 f0 = __half22float2(h[0]);
  float2 f1 = __half22float2(h[1]);
  float2 f2 = __half22float2(h[2]);
  float2 f3 = __half22float2(h[3]);
  a.x0 += f0.x; a.x1 += f0.y; a.x2 += f1.x; a.x3 += f1.y;
  a.x4 += f2.x; a.x5 += f2.y; a.x6 += f3.x; a.x7 += f3.y;
}

template <int C, bool RELU, bool OUT16>
__global__ __launch_bounds__(256) void gather_kernel(const int* __restrict__ cnt,
                                                     const int* __restrict__ pad_csr,
                                                     const float* __restrict__ dinv,
                                                     const __half* __restrict__ Hs,
                                                     const float* __restrict__ bias,
                                                     const int* __restrict__ ovf_cnt,
                                                     const int2* __restrict__ ovf,
                                                     void* __restrict__ OutPtr) {
  constexpr int TPN = C / 16;  // threads per node (8 or 4)
  int gid = blockIdx.x * 256 + threadIdx.x;
  int i = gid / TPN;
  int c16 = (gid % TPN) * 16;
  if (i >= NNODES) return;

  const float di = dinv[i];
  const int deg = cnt[i];
  const int beg = i * CAP;
  const int end = beg + min(deg, CAP);
  const int* __restrict__ lst = pad_csr;
  const __half* __restrict__ Hb = Hs + c16;  // this lane's channel window

  F8 a0l = {}, a0h = {}, a1l = {}, a1h = {};
  {
    const __half* p = Hb + (size_t)i * C;  // self term (pre-scaled)
    add_h8(a0l, p);
    add_h8(a0h, p + 8);
  }

  int j = beg;
  for (; j + 8 <= end; j += 8) {
    // lists are 256B-aligned and j-beg is a multiple of 8 -> int4-aligned
    int4 sa = *(const int4*)&lst[j];
    int4 sb = *(const int4*)&lst[j + 4];
    const __half* p0 = Hb + (size_t)sa.x * C;
    const __half* p1 = Hb + (size_t)sa.y * C;
    const __half* p2 = Hb + (size_t)sa.z * C;
    const __half* p3 = Hb + (size_t)sa.w * C;
    add_h8(a0l, p0); add_h8(a0h, p0 + 8);
    add_h8(a1l, p1); add_h8(a1h, p1 + 8);
    add_h8(a0l, p2); add_h8(a0h, p2 + 8);
    add_h8(a1l, p3); add_h8(a1h, p3 + 8);
    const __half* p4 = Hb + (size_t)sb.x * C;
    const __half* p5 = Hb + (size_t)sb.y * C;
    const __half* p6 = Hb + (size_t)sb.z * C;
    const __half* p7 = Hb + (size_t)sb.w * C;
    add_h8(a0l, p4); add_h8(a0h, p4 + 8);
    add_h8(a1l, p5); add_h8(a1h, p5 + 8);
    add_h8(a0l, p6); add_h8(a0h, p6 + 8);
    add_h8(a1l, p7); add_h8(a1h, p7 + 8);
  }
  for (; j + 2 <= end; j += 2) {
    const __half* p0 = Hb + (size_t)lst[j] * C;
    const __half* p1 = Hb + (size_t)lst[j + 1] * C;
    add_h8(a0l, p0); add_h8(a0h, p0 + 8);
    add_h8(a1l, p1); add_h8(a1h, p1 + 8);
  }
  if (j < end) {
    const __half* p0 = Hb + (size_t)lst[j] * C;
    add_h8(a0l, p0); add_h8(a0h, p0 + 8);
  }

  if (deg > CAP) {  // exactness guard; never taken for Poisson(16) degrees
    int n = min(*ovf_cnt, OVF_MAX);
    for (int t = 0; t < n; ++t) {
      int2 p = ovf[t];
      if (p.y == i) {
        const __half* q = Hb + (size_t)p.x * C;
        add_h8(a0l, q); add_h8(a0h, q + 8);
      }
    }
  }

  float s0 = a0l.x0 + a1l.x0, s1 = a0l.x1 + a1l.x1;
  float s2 = a0l.x2 + a1l.x2, s3 = a0l.x3 + a1l.x3;
  float s4 = a0l.x4 + a1l.x4, s5 = a0l.x5 + a1l.x5;
  float s6 = a0l.x6 + a1l.x6, s7 = a0l.x7 + a1l.x7;
  float s8 = a0h.x0 + a1h.x0, s9 = a0h.x1 + a1h.x1;
  float s10 = a0h.x2 + a1h.x2, s11 = a0h.x3 + a1h.x3;
  float s12 = a0h.x4 + a1h.x4, s13 = a0h.x5 + a1h.x5;
  float s14 = a0h.x6 + a1h.x6, s15 = a0h.x7 + a1h.x7;

  float4 b0 = *(const float4*)&bias[c16];
  float4 b1 = *(const float4*)&bias[c16 + 4];
  float4 b2 = *(const float4*)&bias[c16 + 8];
  float4 b3 = *(const float4*)&bias[c16 + 12];
  float o0 = fmaf(s0, di, b0.x),  o1 = fmaf(s1, di, b0.y);
  float o2 = fmaf(s2, di, b0.z),  o3 = fmaf(s3, di, b0.w);
  float o4 = fmaf(s4, di, b1.x),  o5 = fmaf(s5, di, b1.y);
  float o6 = fmaf(s6, di, b1.z),  o7 = fmaf(s7, di, b1.w);
  float o8 = fmaf(s8, di, b2.x),  o9 = fmaf(s9, di, b2.y);
  float o10 = fmaf(s10, di, b2.z), o11 = fmaf(s11, di, b2.w);
  float o12 = fmaf(s12, di, b3.x), o13 = fmaf(s13, di, b3.y);
  float o14 = fmaf(s14, di, b3.z), o15 = fmaf(s15, di, b3.w);
  if (RELU) {
    o0 = o0 > 0.f ? o0 : 0.f;   o1 = o1 > 0.f ? o1 : 0.f;
    o2 = o2 > 0.f ? o2 : 0.f;   o3 = o3 > 0.f ? o3 : 0.f;
    o4 = o4 > 0.f ? o4 : 0.f;   o5 = o5 > 0.f ? o5 : 0.f;
    o6 = o6 > 0.f ? o6 : 0.f;   o7 = o7 > 0.f ? o7 : 0.f;
    o8 = o8 > 0.f ? o8 : 0.f;   o9 = o9 > 0.f ? o9 : 0.f;
    o10 = o10 > 0.f ? o10 : 0.f; o11 = o11 > 0.f ? o11 : 0.f;
    o12 = o12 > 0.f ? o12 : 0.f; o13 = o13 > 0.f ? o13 : 0.f;
    o14 = o14 > 0.f ? o14 : 0.f; o15 = o15 > 0.f ? o15 : 0.f;
  }
  if (OUT16) {
    _Float16* Out = (_Float16*)OutPtr + (size_t)i * C + c16;
    half8 hv0 = {(_Float16)o0, (_Float16)o1, (_Float16)o2, (_Float16)o3,
                 (_Float16)o4, (_Float16)o5, (_Float16)o6, (_Float16)o7};
    half8 hv1 = {(_Float16)o8, (_Float16)o9, (_Float16)o10, (_Float16)o11,
                 (_Float16)o12, (_Float16)o13, (_Float16)o14, (_Float16)o15};
    *(half8*)Out = hv0;
    *(half8*)(Out + 8) = hv1;
  } else {
    float* Out = (float*)OutPtr + (size_t)i * C + c16;
    *(float4*)Out = make_float4(o0, o1, o2, o3);
    *(float4*)(Out + 4) = make_float4(o4, o5, o6, o7);
    *(float4*)(Out + 8) = make_float4(o8, o9, o10, o11);
    *(float4*)(Out + 12) = make_float4(o12, o13, o14, o15);
  }
}

// ===========================================================================
// MFMA fp16 GEMM: Hout[M,N] = fp16( (X[M,K] @ W[K,N]) * scale[row] )
// 64-row M-tile per block, 4 waves x 16 rows. W in LDS transposed [n][k],
// A-tile in LDS [m][k], both fp16 with +8-half row pad.
// Fragment layouts (HW-verified m89/m91/m120):
//   A: m=lane&15, k=8*(lane>>4)+j ; B: n=lane&15, same k ;
//   D: row=4*(lane>>4)+reg, col=lane&15.
// ===========================================================================
template <int K, int N, bool A_F16>
__global__ __launch_bounds__(256) void mfma_gemm_kernel(const void* __restrict__ Xv,
                                                        const float* __restrict__ Wm,
                                                        const float* __restrict__ scale,
                                                        _Float16* __restrict__ Hout,
                                                        int M) {
  constexpr int KP = K + 8;  // padded row stride in halves (136)
  __shared__ alignas(16) _Float16 Alds[64 * KP];
  __shared__ alignas(16) _Float16 Wlds[N * KP];

  const int tid = threadIdx.x;
  const int row0 = blockIdx.x * 64;

  // ---- stage W (KxN fp32 row-major) -> Wlds[n][k] fp16, 4x4 transpose ----
  constexpr int TILES = (K / 4) * (N / 4);
  for (int tile = tid; tile < TILES; tile += 256) {
    int kt = tile / (N / 4);
    int nt = tile % (N / 4);
    const float* wp = &Wm[(4 * kt) * N + 4 * nt];
    float4 r0 = *(const float4*)(wp);
    float4 r1 = *(const float4*)(wp + N);
    float4 r2 = *(const float4*)(wp + 2 * N);
    float4 r3 = *(const float4*)(wp + 3 * N);
    half4 c0 = {(_Float16)r0.x, (_Float16)r1.x, (_Float16)r2.x, (_Float16)r3.x};
    half4 c1 = {(_Float16)r0.y, (_Float16)r1.y, (_Float16)r2.y, (_Float16)r3.y};
    half4 c2 = {(_Float16)r0.z, (_Float16)r1.z, (_Float16)r2.z, (_Float16)r3.z};
    half4 c3 = {(_Float16)r0.w, (_Float16)r1.w, (_Float16)r2.w, (_Float16)r3.w};
    *(half4*)&Wlds[(4 * nt + 0) * KP + 4 * kt] = c0;
    *(half4*)&Wlds[(4 * nt + 1) * KP + 4 * kt] = c1;
    *(half4*)&Wlds[(4 * nt + 2) * KP + 4 * kt] = c2;
    *(half4*)&Wlds[(4 * nt + 3) * KP + 4 * kt] = c3;
  }

  // ---- stage A tile (64 x K) -> Alds fp16 ----
  if (A_F16) {
    const _Float16* Xh = (const _Float16*)Xv;
    constexpr int H8PR = K / 8;  // half8 per row (16)
    constexpr int TOT = 64 * H8PR;
    for (int idx = tid; idx < TOT; idx += 256) {
      int lr = idx / H8PR;
      int c8 = (idx % H8PR) * 8;
      int gr = row0 + lr;
      if (gr > M - 1) gr = M - 1;
      int4 v = *(const int4*)&Xh[(size_t)gr * K + c8];
      *(int4*)&Alds[lr * KP + c8] = v;
    }
  } else {
    const float* Xf = (const float*)Xv;
    constexpr int F4PR = K / 4;  // float4 per row (32)
    constexpr int TOT = 64 * F4PR;
    for (int idx = tid; idx < TOT; idx += 256) {
      int lr = idx / F4PR;
      int c4 = (idx % F4PR) * 4;
      int gr = row0 + lr;
      if (gr > M - 1) gr = M - 1;
      float4 v = *(const float4*)&Xf[(size_t)gr * K + c4];
      half4 h = {(_Float16)v.x, (_Float16)v.y, (_Float16)v.z, (_Float16)v.w};
      *(half4*)&Alds[lr * KP + c4] = h;
    }
  }
  __syncthreads();

  // ---- compute ----
  const int w = tid >> 6;
  const int lane = tid & 63;
  const int g = lane >> 4;
  const int mi = lane & 15;
  constexpr int NT = N / 16;

  floatx4 acc[NT];
#pragma unroll
  for (int t = 0; t < NT; ++t) acc[t] = (floatx4){0.f, 0.f, 0.f, 0.f};

  const _Float16* arow = &Alds[(w * 16 + mi) * KP];
#pragma unroll
  for (int ks = 0; ks < K / 32; ++ks) {
    half8 a = *(const half8*)(arow + ks * 32 + g * 8);
#pragma unroll
    for (int t = 0; t < NT; ++t) {
      half8 b = *(const half8*)&Wlds[(t * 16 + mi) * KP + ks * 32 + g * 8];
      acc[t] = __builtin_amdgcn_mfma_f32_16x16x32_f16(a, b, acc[t], 0, 0, 0);
    }
  }

  // ---- epilogue: scale by dinv[row], store fp16 ----
#pragma unroll
  for (int r = 0; r < 4; ++r) {
    int grow = row0 + w * 16 + 4 * g + r;
    if (grow < M) {
      float s = scale[grow];
      _Float16* orow = Hout + (size_t)grow * N + mi;
#pragma unroll
      for (int t = 0; t < NT; ++t) orow[t * 16] = (_Float16)(acc[t][r] * s);
    }
  }
}

// ===========================================================================
// Launch
// ===========================================================================
extern "C" void kernel_launch(void* const* d_in, const int* in_sizes, int n_in,
                              void* d_out, int out_size, void* d_ws, size_t ws_size,
                              hipStream_t stream) {
  const float* x = (const float*)d_in[0];
  const void* eidx = d_in[1];
  const float* W1 = (const float*)d_in[2];
  const float* b1 = (const float*)d_in[3];
  const float* W2 = (const float*)d_in[4];
  const float* b2 = (const float*)d_in[5];
  float* out = (float*)d_out;
  char* ws = (char*)d_ws;

  // Workspace layout (512B-aligned, ~87.4 MB; harness provides >=110 MB):
  int*      flag     = (int*)(ws + 0);             //         4 B
  int*      ovf_cnt  = (int*)(ws + 512);           //         4 B
  int*      ovfA_cnt = (int*)(ws + 1024);          //         4 B
  int*      bcnt     = (int*)(ws + 1536);          //    50,048 B (782*16, padded)
  int*      cnt      = (int*)(ws + 52224);         //   400,000 B
  float*    dinv     = (float*)(ws + 452608);      //   400,000 B
  int2*     ovf      = (int2*)(ws + 852992);       //    32,768 B
  int2*     ovfA     = (int2*)(ws + 885760);       //    32,768 B
  unsigned* buf      = (unsigned*)(ws + 918528);   // 9,609,216 B (782*3072*4)
  int*      pad_csr  = (int*)(ws + 10528256);      // 25,600,000 B (100k x 64)
  _Float16* h1       = (_Float16*)(ws + 36128256); // 25,600,000 B (fp16 Hs)
  _Float16* hidden   = (_Float16*)(ws + 61728256); // 25,600,000 B (fp16)
  _Float16* h2 = h1;

  detect_idx_kernel<<<1, 64, 0, stream>>>(eidx, flag);
  zero_misc_kernel<<<(NB * BCNT_STRIDE + 255) / 256, 256, 0, stream>>>(bcnt, ovf_cnt,
                                                                       ovfA_cnt);
  binA_kernel<<<NBLK_A, 256, 0, stream>>>(eidx, flag, bcnt, buf, ovfA_cnt, ovfA);
  binB_kernel<<<NB, 256, 0, stream>>>(bcnt, buf, cnt, dinv, pad_csr, ovf_cnt, ovf);
  fixup_kernel<<<1, 256, 0, stream>>>(ovfA_cnt, ovfA, cnt, dinv, pad_csr,
                                      ovf_cnt, ovf);

  // Layer 1: Hs1 = fp16((x @ W1) * dinv); hidden = fp16(relu(di*(Hs1[i]+sum)+b1))
  const int GB = (NNODES + 63) / 64;  // 1563 M-tiles
  mfma_gemm_kernel<IN_C, HID_C, false>
      <<<GB, 256, 0, stream>>>(x, W1, dinv, h1, NNODES);
  gather_kernel<HID_C, true, true>
      <<<(NNODES * (HID_C / 16) + 255) / 256, 256, 0, stream>>>(cnt, pad_csr, dinv,
                                                                (const __half*)h1, b1,
                                                                ovf_cnt, ovf, hidden);
  // Layer 2: Hs2 = fp16((hidden @ W2) * dinv); out = di*(Hs2[i]+sum)+b2 (fp32)
  mfma_gemm_kernel<HID_C, OUT_C, true>
      <<<GB, 256, 0, stream>>>(hidden, W2, dinv, h2, NNODES);
  gather_kernel<OUT_C, false, false>
      <<<(NNODES * (OUT_C / 16) + 255) / 256, 256, 0, stream>>>(cnt, pad_csr, dinv,
                                                                (const __half*)h2, b2,
                                                                ovf_cnt, ovf, out);
}